// Round 7
// baseline (174.500 us; speedup 1.0000x reference)
//
#include <hip/hip_runtime.h>

#define NSPK 256
#define MUTT 64
#define DDIM 1024
#define NROW (NSPK * MUTT)   // 16384

using frag_ab = __attribute__((ext_vector_type(8))) short;   // 8 bf16 (4 VGPRs)
using frag_cd = __attribute__((ext_vector_type(4))) float;   // 4 fp32 acc

static __device__ __forceinline__ unsigned short f32_to_bf16(float f) {
    unsigned int u = __float_as_uint(f);
    return (unsigned short)((u + 0x7FFFu + ((u >> 16) & 1u)) >> 16);   // RNE
}
static __device__ __forceinline__ unsigned int pack2(float a, float b) {
    return (unsigned)f32_to_bf16(a) | ((unsigned)f32_to_bf16(b) << 16);
}
static __device__ __forceinline__ void gload16(const void* g, void* l) {
    __builtin_amdgcn_global_load_lds(
        (const __attribute__((address_space(1))) unsigned int*)g,
        (__attribute__((address_space(3))) unsigned int*)l, 16, 0, 0);
}

// ======================= FAST PATH =======================

// k_prep: grid (NSPK, 4), 256 thr, 16 rows/block.
__global__ void __launch_bounds__(256) k_prep(const float* __restrict__ emb,
                                              float* __restrict__ Sp,
                                              unsigned short* __restrict__ ebf,
                                              float* __restrict__ qg) {
    const int j = blockIdx.x;
    const int h = blockIdx.y;
    const int t = threadIdx.x;
    const int lane = t & 63, wave = t >> 6;
    const size_t rowbase = (size_t)j * MUTT + (size_t)h * 16;
    const float* src = emb + rowbase * DDIM + (size_t)t * 4;
    unsigned short* edst = ebf + rowbase * DDIM + (size_t)t * 4;
    __shared__ float qws[16][4];
    float4 s = make_float4(0.f, 0.f, 0.f, 0.f);
    #pragma unroll
    for (int m = 0; m < 16; ++m) {
        float4 v = *(const float4*)(src + (size_t)m * DDIM);
        s.x += v.x; s.y += v.y; s.z += v.z; s.w += v.w;
        float qp = v.x * v.x + v.y * v.y + v.z * v.z + v.w * v.w;
        #pragma unroll
        for (int off = 32; off > 0; off >>= 1) qp += __shfl_down(qp, off, 64);
        if (lane == 0) qws[m][wave] = qp;
        *(uint2*)(edst + (size_t)m * DDIM) = make_uint2(pack2(v.x, v.y), pack2(v.z, v.w));
    }
    __syncthreads();
    if (t < 16) qg[rowbase + t] = qws[t][0] + qws[t][1] + qws[t][2] + qws[t][3];
    *(float4*)(Sp + ((size_t)h * NSPK + j) * DDIM + (size_t)t * 4) = s;
}

template <int P>
__global__ void k_center(const float* __restrict__ Sp, unsigned short* __restrict__ cbf,
                         float* __restrict__ normS2g, float* __restrict__ normSg) {
    const int j = blockIdx.x;
    const int t = threadIdx.x;
    float4 v = make_float4(0.f, 0.f, 0.f, 0.f);
    #pragma unroll
    for (int p = 0; p < P; ++p) {
        float4 a = *(const float4*)(Sp + ((size_t)p * NSPK + j) * DDIM + (size_t)t * 4);
        v.x += a.x; v.y += a.y; v.z += a.z; v.w += a.w;
    }
    float sq = v.x * v.x + v.y * v.y + v.z * v.z + v.w * v.w;
    #pragma unroll
    for (int off = 32; off > 0; off >>= 1) sq += __shfl_down(sq, off, 64);
    __shared__ float ws[4];
    __shared__ float sc_sh;
    const int lane = t & 63, wave = t >> 6;
    if (lane == 0) ws[wave] = sq;
    __syncthreads();
    if (t == 0) {
        float tot = ws[0] + ws[1] + ws[2] + ws[3];
        normS2g[j] = tot;
        normSg[j]  = sqrtf(tot);
        float msq = tot * (1.0f / 4096.0f);
        sc_sh = rsqrtf(fmaxf(msq, 1e-12f)) * (1.0f / 64.0f);
    }
    __syncthreads();
    const float sc = sc_sh;
    *(uint2*)(cbf + (size_t)j * DDIM + (size_t)t * 4) =
        make_uint2(pack2(v.x * sc, v.y * sc), pack2(v.z * sc, v.w * sc));
}

// k_gemm7: 16 rows x 256 cols per block; grid 1024 (4 blocks/CU, 16 waves/CU).
// A (16 x 1024 bf16 = 32 KB) in LDS full-K, staged once (1 barrier). K-loop is
// barrier-free, #pragma unroll 4, with a depth-4 B register pipeline (static %4).
// A ds_read_b128 XOR-swizzled -> 2-way bank alias only (free).
__global__ void __launch_bounds__(256, 4)
k_gemm7(const unsigned short* __restrict__ ebf, const unsigned short* __restrict__ cbf,
        const float* __restrict__ qg, const float* __restrict__ n2g,
        const float* __restrict__ n1g,
        const float* __restrict__ wp, const float* __restrict__ bp,
        float* __restrict__ out) {
    __shared__ unsigned short As[16 * DDIM];   // 32 KB

    const int tid = threadIdx.x, lane = tid & 63, wave = tid >> 6;
    const int row0 = blockIdx.x * 16;
    const int quad = lane >> 4;
    const int m16 = lane & 15;

    // ---- stage A: 16 rows x 128 chunks (16 B each) = 8 rounds x 256 thr ----
    // LDS chunk p of row rw holds global chunk p^(rw&7).
    {
        const char* ag = (const char*)(ebf + (size_t)row0 * DDIM);
        #pragma unroll
        for (int r = 0; r < 8; ++r) {
            const int c = r * 256 + tid;           // 0..2047
            const int rw = c >> 7;                 // row 0..15 (wave-uniform)
            const int p = c & 127;
            gload16(ag + rw * 2048 + ((p ^ (rw & 7)) << 4),
                    (char*)As + rw * 2048 + (p << 4));
        }
    }

    // B frag addressing: wave owns cols [wave*64, wave*64+64)
    const char* bg[4];
    #pragma unroll
    for (int cc = 0; cc < 4; ++cc)
        bg[cc] = (const char*)cbf + (size_t)(wave * 64 + cc * 16 + m16) * 2048 + quad * 16;

    frag_cd acc[4];
    #pragma unroll
    for (int cc = 0; cc < 4; ++cc) acc[cc] = (frag_cd){0.f, 0.f, 0.f, 0.f};

    // depth-4 B register pipeline (bounded: 64 VGPRs)
    frag_ab bf[4][4];
    #pragma unroll
    for (int d = 0; d < 4; ++d)
        #pragma unroll
        for (int cc = 0; cc < 4; ++cc)
            bf[d][cc] = *(const frag_ab*)(bg[cc] + d * 64);

    __syncthreads();   // drains A staging; the only barrier

    #pragma unroll 4
    for (int ks = 0; ks < 32; ++ks) {
        frag_ab af;
        {
            const int rw = m16;
            const int chunk = (ks * 4 + quad) ^ (rw & 7);
            af = *(const frag_ab*)((const char*)As + rw * 2048 + (chunk << 4));
        }
        frag_ab cur[4];
        #pragma unroll
        for (int cc = 0; cc < 4; ++cc) cur[cc] = bf[ks & 3][cc];
        if (ks + 4 < 32) {
            #pragma unroll
            for (int cc = 0; cc < 4; ++cc)
                bf[ks & 3][cc] = *(const frag_ab*)(bg[cc] + (ks + 4) * 64);
        }
        #pragma unroll
        for (int cc = 0; cc < 4; ++cc)
            acc[cc] = __builtin_amdgcn_mfma_f32_16x16x32_bf16(af, cur[cc], acc[cc], 0, 0, 0);
    }

    const float wv = wp[0], bv = bp[0];
    const int jspk = row0 >> 6;            // 16-row block lies inside one speaker
    const float ns2 = n2g[jspk], ns = n1g[jspk];
    const int rbase = quad << 2;
    #pragma unroll
    for (int cc = 0; cc < 4; ++cc) {
        int col = wave * 64 + cc * 16 + m16;
        frag_cd v = acc[cc];
        #pragma unroll
        for (int r2 = 0; r2 < 4; ++r2) {
            int grow = row0 + rbase + r2;
            float val = v[r2];
            if (col == jspk) {
                float q = qg[grow];
                float rd = val * ns;
                float den2 = ns2 - 2.f * rd + q;
                val = (rd - q) * rsqrtf(fmaxf(den2, 1e-12f));
            }
            out[(size_t)grow * NSPK + col] = wv * val + bv;
        }
    }
}

// ======================= FALLBACK (small ws) =======================

__global__ void k_sums(const float* __restrict__ emb, float* __restrict__ Sp) {
    const int j = blockIdx.x;
    const int h = blockIdx.y;
    const int c = threadIdx.x;
    const float* base = emb + ((size_t)j * MUTT + (size_t)h * 32) * DDIM + (size_t)c * 4;
    float4 acc = make_float4(0.f, 0.f, 0.f, 0.f);
    #pragma unroll 8
    for (int m = 0; m < 32; ++m) {
        float4 v = *(const float4*)(base + (size_t)m * DDIM);
        acc.x += v.x; acc.y += v.y; acc.z += v.z; acc.w += v.w;
    }
    *(float4*)(Sp + ((size_t)h * NSPK + j) * DDIM + (size_t)c * 4) = acc;
}

__global__ void __launch_bounds__(256)
k_gemm_old(const float* __restrict__ emb, const unsigned short* __restrict__ cbf,
           const float* __restrict__ normS2g, const float* __restrict__ normSg,
           const float* __restrict__ wp, const float* __restrict__ bp,
           float* __restrict__ out) {
    __shared__ unsigned short Asm[32][32];
    __shared__ unsigned short Bsm[256][32];
    __shared__ float qpart[32][8];
    __shared__ float qfin[32];
    const int tid = threadIdx.x, lane = tid & 63, wave = tid >> 6;
    const int row0 = blockIdx.x * 32;
    const int jspk = row0 >> 6;
    frag_cd acc[2][4];
    #pragma unroll
    for (int rr = 0; rr < 2; ++rr)
        #pragma unroll
        for (int cc = 0; cc < 4; ++cc) acc[rr][cc] = (frag_cd){0.f, 0.f, 0.f, 0.f};
    const int ar = tid >> 3, ak = (tid & 7) << 2;
    const float* aptr = emb + (size_t)(row0 + ar) * DDIM + ak;
    float qacc = 0.f;
    const int bi = tid >> 2, bk = (tid & 3) << 3;
    const int am = lane & 15, kq = (lane >> 4) << 3;
    for (int k0 = 0; k0 < DDIM; k0 += 32) {
        __syncthreads();
        float4 av = *(const float4*)(aptr + k0);
        qacc += av.x * av.x + av.y * av.y + av.z * av.z + av.w * av.w;
        *(uint2*)&Asm[ar][ak] = make_uint2(pack2(av.x, av.y), pack2(av.z, av.w));
        #pragma unroll
        for (int p = 0; p < 4; ++p) {
            int brow = p * 64 + bi;
            *(uint4*)&Bsm[brow][bk] = *(const uint4*)(cbf + (size_t)brow * DDIM + k0 + bk);
        }
        __syncthreads();
        frag_ab afr[2], bfr[4];
        #pragma unroll
        for (int rr = 0; rr < 2; ++rr) afr[rr] = *(const frag_ab*)&Asm[rr * 16 + am][kq];
        #pragma unroll
        for (int cc = 0; cc < 4; ++cc) bfr[cc] = *(const frag_ab*)&Bsm[wave * 64 + cc * 16 + am][kq];
        #pragma unroll
        for (int rr = 0; rr < 2; ++rr)
            #pragma unroll
            for (int cc = 0; cc < 4; ++cc)
                acc[rr][cc] = __builtin_amdgcn_mfma_f32_16x16x32_bf16(afr[rr], bfr[cc], acc[rr][cc], 0, 0, 0);
    }
    qpart[ar][tid & 7] = qacc;
    __syncthreads();
    if (tid < 32) {
        float s = 0.f;
        #pragma unroll
        for (int u = 0; u < 8; ++u) s += qpart[tid][u];
        qfin[tid] = s;
    }
    __syncthreads();
    const float wv = wp[0], bv = bp[0];
    const float ns2 = normS2g[jspk], ns = normSg[jspk];
    #pragma unroll
    for (int rr = 0; rr < 2; ++rr) {
        int rbase = rr * 16 + ((lane >> 4) << 2);
        #pragma unroll
        for (int cc = 0; cc < 4; ++cc) {
            int col = wave * 64 + cc * 16 + (lane & 15);
            frag_cd v = acc[rr][cc];
            #pragma unroll
            for (int r2 = 0; r2 < 4; ++r2) {
                int lrow = rbase + r2;
                float val = v[r2];
                if (col == jspk) {
                    float q = qfin[lrow];
                    float rd = val * ns;
                    float den2 = ns2 - 2.f * rd + q;
                    val = (rd - q) * rsqrtf(fmaxf(den2, 1e-12f));
                }
                out[(size_t)(row0 + lrow) * NSPK + col] = wv * val + bv;
            }
        }
    }
}

extern "C" void kernel_launch(void* const* d_in, const int* in_sizes, int n_in,
                              void* d_out, int out_size, void* d_ws, size_t ws_size,
                              hipStream_t stream) {
    const float* emb = (const float*)d_in[0];
    const float* w   = (const float*)d_in[1];
    const float* b   = (const float*)d_in[2];
    float* out = (float*)d_out;

    const size_t sz_Sp  = (size_t)4 * NSPK * DDIM * 4;
    const size_t sz_ebf = (size_t)NROW * DDIM * 2;
    const size_t sz_cbf = (size_t)NSPK * DDIM * 2;
    const size_t sz_qg  = (size_t)NROW * 4;
    const size_t need = sz_Sp + sz_ebf + sz_cbf + sz_qg + 2 * NSPK * 4;

    if (ws_size >= need) {
        char* p = (char*)d_ws;
        float* Sp = (float*)p;              p += sz_Sp;
        unsigned short* ebf = (unsigned short*)p; p += sz_ebf;
        unsigned short* cbf = (unsigned short*)p; p += sz_cbf;
        float* qg = (float*)p;              p += sz_qg;
        float* n2 = (float*)p;              p += NSPK * 4;
        float* n1 = n2 + NSPK;
        k_prep<<<dim3(NSPK, 4), 256, 0, stream>>>(emb, Sp, ebf, qg);
        k_center<4><<<NSPK, 256, 0, stream>>>(Sp, cbf, n2, n1);
        k_gemm7<<<NROW / 16, 256, 0, stream>>>(ebf, cbf, qg, n2, n1, w, b, out);
    } else {
        float* Sp = (float*)d_ws;
        unsigned short* cbf = (unsigned short*)(Sp + 2 * NSPK * DDIM);
        float* n2 = (float*)(cbf + NSPK * DDIM);
        float* n1 = n2 + NSPK;
        k_sums<<<dim3(NSPK, 2), 256, 0, stream>>>(emb, Sp);
        k_center<2><<<NSPK, 256, 0, stream>>>(Sp, cbf, n2, n1);
        k_gemm_old<<<NROW / 32, 256, 0, stream>>>(emb, cbf, n2, n1, w, b, out);
    }
}

// Round 8
// 137.135 us; speedup vs baseline: 1.2725x; 1.2725x over previous
//
#include <hip/hip_runtime.h>

#define NSPK 256
#define MUTT 64
#define DDIM 1024
#define NROW (NSPK * MUTT)   // 16384

using frag_ab = __attribute__((ext_vector_type(8))) short;   // 8 bf16 (4 VGPRs)
using frag_cd = __attribute__((ext_vector_type(4))) float;   // 4 fp32 acc

static __device__ __forceinline__ unsigned short f32_to_bf16(float f) {
    unsigned int u = __float_as_uint(f);
    return (unsigned short)((u + 0x7FFFu + ((u >> 16) & 1u)) >> 16);   // RNE
}
static __device__ __forceinline__ unsigned int pack2(float a, float b) {
    return (unsigned)f32_to_bf16(a) | ((unsigned)f32_to_bf16(b) << 16);
}
static __device__ __forceinline__ void gload16(const void* g, void* l) {
    __builtin_amdgcn_global_load_lds(
        (const __attribute__((address_space(1))) unsigned int*)g,
        (__attribute__((address_space(3))) unsigned int*)l, 16, 0, 0);
}

// ======================= FAST PATH =======================

// k_prep: grid (NSPK, 4), 256 thr, 16 rows/block. Sums, bf16 cast, per-row q.
__global__ void __launch_bounds__(256) k_prep(const float* __restrict__ emb,
                                              float* __restrict__ Sp,
                                              unsigned short* __restrict__ ebf,
                                              float* __restrict__ qg) {
    const int j = blockIdx.x;
    const int h = blockIdx.y;
    const int t = threadIdx.x;
    const int lane = t & 63, wave = t >> 6;
    const size_t rowbase = (size_t)j * MUTT + (size_t)h * 16;
    const float* src = emb + rowbase * DDIM + (size_t)t * 4;
    unsigned short* edst = ebf + rowbase * DDIM + (size_t)t * 4;
    __shared__ float qws[16][4];
    float4 s = make_float4(0.f, 0.f, 0.f, 0.f);
    #pragma unroll
    for (int m = 0; m < 16; ++m) {
        float4 v = *(const float4*)(src + (size_t)m * DDIM);
        s.x += v.x; s.y += v.y; s.z += v.z; s.w += v.w;
        float qp = v.x * v.x + v.y * v.y + v.z * v.z + v.w * v.w;
        #pragma unroll
        for (int off = 32; off > 0; off >>= 1) qp += __shfl_down(qp, off, 64);
        if (lane == 0) qws[m][wave] = qp;
        *(uint2*)(edst + (size_t)m * DDIM) = make_uint2(pack2(v.x, v.y), pack2(v.z, v.w));
    }
    __syncthreads();
    if (t < 16) qg[rowbase + t] = qws[t][0] + qws[t][1] + qws[t][2] + qws[t][3];
    *(float4*)(Sp + ((size_t)h * NSPK + j) * DDIM + (size_t)t * 4) = s;
}

// k_center<P, PACKED>: sum P partials -> centers. PACKED=1 writes MFMA-fragment
// order: short index ((k>>3)*256 + j)*8 + (k&7)  (so B-frag loads coalesce).
template <int P, int PACKED>
__global__ void k_center(const float* __restrict__ Sp, unsigned short* __restrict__ cbf,
                         float* __restrict__ normS2g, float* __restrict__ normSg) {
    const int j = blockIdx.x;
    const int t = threadIdx.x;                 // k = 4t .. 4t+3
    float4 v = make_float4(0.f, 0.f, 0.f, 0.f);
    #pragma unroll
    for (int p = 0; p < P; ++p) {
        float4 a = *(const float4*)(Sp + ((size_t)p * NSPK + j) * DDIM + (size_t)t * 4);
        v.x += a.x; v.y += a.y; v.z += a.z; v.w += a.w;
    }
    float sq = v.x * v.x + v.y * v.y + v.z * v.z + v.w * v.w;
    #pragma unroll
    for (int off = 32; off > 0; off >>= 1) sq += __shfl_down(sq, off, 64);
    __shared__ float ws[4];
    __shared__ float sc_sh;
    const int lane = t & 63, wave = t >> 6;
    if (lane == 0) ws[wave] = sq;
    __syncthreads();
    if (t == 0) {
        float tot = ws[0] + ws[1] + ws[2] + ws[3];
        normS2g[j] = tot;
        normSg[j]  = sqrtf(tot);
        float msq = tot * (1.0f / 4096.0f);
        sc_sh = rsqrtf(fmaxf(msq, 1e-12f)) * (1.0f / 64.0f);
    }
    __syncthreads();
    const float sc = sc_sh;
    uint2 pk = make_uint2(pack2(v.x * sc, v.y * sc), pack2(v.z * sc, v.w * sc));
    if (PACKED) {
        unsigned short* dst = cbf + (((size_t)(t >> 1) * 256 + j) * 8 + (size_t)(t & 1) * 4);
        *(uint2*)dst = pk;
    } else {
        *(uint2*)(cbf + (size_t)j * DDIM + (size_t)t * 4) = pk;
    }
}

// k_gemm8: 16 rows x 256 cols, grid 1024 (4 blocks/CU, 16 waves/CU).
// A (16 x 1024 bf16 = 32 KB) staged once via gload16 + XOR swizzle (1 barrier).
// B streamed from PACKED layout: each frag load = 16 lanes x 16 B contiguous.
// No software pipeline (zero-distance loads); TLP hides L2 latency.
__global__ void __launch_bounds__(256, 4)
k_gemm8(const unsigned short* __restrict__ ebf, const unsigned short* __restrict__ cbfp,
        const float* __restrict__ qg, const float* __restrict__ n2g,
        const float* __restrict__ n1g,
        const float* __restrict__ wp, const float* __restrict__ bp,
        float* __restrict__ out) {
    __shared__ unsigned short As[16 * DDIM];   // 32 KB

    const int tid = threadIdx.x, lane = tid & 63, wave = tid >> 6;
    const int row0 = blockIdx.x * 16;
    const int quad = lane >> 4;
    const int m16 = lane & 15;

    // ---- stage A: 16 rows x 128 chunks(16B); LDS chunk p of row rw = global p^(rw&7)
    {
        const char* ag = (const char*)(ebf + (size_t)row0 * DDIM);
        char* Ab = (char*)As;
        #pragma unroll
        for (int r = 0; r < 8; ++r) {
            const int c = r * 256 + tid;           // 0..2047
            const int rw = c >> 7;                 // wave-uniform row
            const int p = c & 127;
            gload16(ag + rw * 2048 + ((p ^ (rw & 7)) << 4), Ab + rw * 2048 + (p << 4));
        }
    }

    // B addressing (packed): byte addr = ((ks*4+quad)*256 + col) * 16
    const char* bq[4];
    #pragma unroll
    for (int cc = 0; cc < 4; ++cc)
        bq[cc] = (const char*)cbfp + ((size_t)quad * 256 + (wave * 64 + cc * 16 + m16)) * 16;

    frag_cd acc[4];
    #pragma unroll
    for (int cc = 0; cc < 4; ++cc) acc[cc] = (frag_cd){0.f, 0.f, 0.f, 0.f};

    __syncthreads();   // drains A staging; the only barrier

    const char* Ar = (const char*)As + m16 * 2048;   // this lane's A row
    const int asw = m16 & 7;
    #pragma unroll 2
    for (int ks = 0; ks < 32; ++ks) {
        frag_ab af = *(const frag_ab*)(Ar + ((((ks << 2) + quad) ^ asw) << 4));
        frag_ab bf0 = *(const frag_ab*)(bq[0] + (size_t)ks * 16384);
        frag_ab bf1 = *(const frag_ab*)(bq[1] + (size_t)ks * 16384);
        frag_ab bf2 = *(const frag_ab*)(bq[2] + (size_t)ks * 16384);
        frag_ab bf3 = *(const frag_ab*)(bq[3] + (size_t)ks * 16384);
        acc[0] = __builtin_amdgcn_mfma_f32_16x16x32_bf16(af, bf0, acc[0], 0, 0, 0);
        acc[1] = __builtin_amdgcn_mfma_f32_16x16x32_bf16(af, bf1, acc[1], 0, 0, 0);
        acc[2] = __builtin_amdgcn_mfma_f32_16x16x32_bf16(af, bf2, acc[2], 0, 0, 0);
        acc[3] = __builtin_amdgcn_mfma_f32_16x16x32_bf16(af, bf3, acc[3], 0, 0, 0);
    }

    const float wv = wp[0], bv = bp[0];
    const int jspk = row0 >> 6;
    const float ns2 = n2g[jspk], ns = n1g[jspk];
    const int rbase = quad << 2;
    #pragma unroll
    for (int cc = 0; cc < 4; ++cc) {
        int col = wave * 64 + cc * 16 + m16;
        frag_cd v = acc[cc];
        #pragma unroll
        for (int r2 = 0; r2 < 4; ++r2) {
            int grow = row0 + rbase + r2;
            float val = v[r2];
            if (col == jspk) {
                float q = qg[grow];
                float rd = val * ns;
                float den2 = ns2 - 2.f * rd + q;
                val = (rd - q) * rsqrtf(fmaxf(den2, 1e-12f));
            }
            out[(size_t)grow * NSPK + col] = wv * val + bv;
        }
    }
}

// ======================= FALLBACK (small ws) =======================

__global__ void k_sums(const float* __restrict__ emb, float* __restrict__ Sp) {
    const int j = blockIdx.x;
    const int h = blockIdx.y;
    const int c = threadIdx.x;
    const float* base = emb + ((size_t)j * MUTT + (size_t)h * 32) * DDIM + (size_t)c * 4;
    float4 acc = make_float4(0.f, 0.f, 0.f, 0.f);
    #pragma unroll 8
    for (int m = 0; m < 32; ++m) {
        float4 v = *(const float4*)(base + (size_t)m * DDIM);
        acc.x += v.x; acc.y += v.y; acc.z += v.z; acc.w += v.w;
    }
    *(float4*)(Sp + ((size_t)h * NSPK + j) * DDIM + (size_t)c * 4) = acc;
}

__global__ void __launch_bounds__(256)
k_gemm_old(const float* __restrict__ emb, const unsigned short* __restrict__ cbf,
           const float* __restrict__ normS2g, const float* __restrict__ normSg,
           const float* __restrict__ wp, const float* __restrict__ bp,
           float* __restrict__ out) {
    __shared__ unsigned short Asm[32][32];
    __shared__ unsigned short Bsm[256][32];
    __shared__ float qpart[32][8];
    __shared__ float qfin[32];
    const int tid = threadIdx.x, lane = tid & 63, wave = tid >> 6;
    const int row0 = blockIdx.x * 32;
    const int jspk = row0 >> 6;
    frag_cd acc[2][4];
    #pragma unroll
    for (int rr = 0; rr < 2; ++rr)
        #pragma unroll
        for (int cc = 0; cc < 4; ++cc) acc[rr][cc] = (frag_cd){0.f, 0.f, 0.f, 0.f};
    const int ar = tid >> 3, ak = (tid & 7) << 2;
    const float* aptr = emb + (size_t)(row0 + ar) * DDIM + ak;
    float qacc = 0.f;
    const int bi = tid >> 2, bk = (tid & 3) << 3;
    const int am = lane & 15, kq = (lane >> 4) << 3;
    for (int k0 = 0; k0 < DDIM; k0 += 32) {
        __syncthreads();
        float4 av = *(const float4*)(aptr + k0);
        qacc += av.x * av.x + av.y * av.y + av.z * av.z + av.w * av.w;
        *(uint2*)&Asm[ar][ak] = make_uint2(pack2(av.x, av.y), pack2(av.z, av.w));
        #pragma unroll
        for (int p = 0; p < 4; ++p) {
            int brow = p * 64 + bi;
            *(uint4*)&Bsm[brow][bk] = *(const uint4*)(cbf + (size_t)brow * DDIM + k0 + bk);
        }
        __syncthreads();
        frag_ab afr[2], bfr[4];
        #pragma unroll
        for (int rr = 0; rr < 2; ++rr) afr[rr] = *(const frag_ab*)&Asm[rr * 16 + am][kq];
        #pragma unroll
        for (int cc = 0; cc < 4; ++cc) bfr[cc] = *(const frag_ab*)&Bsm[wave * 64 + cc * 16 + am][kq];
        #pragma unroll
        for (int rr = 0; rr < 2; ++rr)
            #pragma unroll
            for (int cc = 0; cc < 4; ++cc)
                acc[rr][cc] = __builtin_amdgcn_mfma_f32_16x16x32_bf16(afr[rr], bfr[cc], acc[rr][cc], 0, 0, 0);
    }
    qpart[ar][tid & 7] = qacc;
    __syncthreads();
    if (tid < 32) {
        float s = 0.f;
        #pragma unroll
        for (int u = 0; u < 8; ++u) s += qpart[tid][u];
        qfin[tid] = s;
    }
    __syncthreads();
    const float wv = wp[0], bv = bp[0];
    const float ns2 = normS2g[jspk], ns = normSg[jspk];
    #pragma unroll
    for (int rr = 0; rr < 2; ++rr) {
        int rbase = rr * 16 + ((lane >> 4) << 2);
        #pragma unroll
        for (int cc = 0; cc < 4; ++cc) {
            int col = wave * 64 + cc * 16 + (lane & 15);
            frag_cd v = acc[rr][cc];
            #pragma unroll
            for (int r2 = 0; r2 < 4; ++r2) {
                int lrow = rbase + r2;
                float val = v[r2];
                if (col == jspk) {
                    float q = qfin[lrow];
                    float rd = val * ns;
                    float den2 = ns2 - 2.f * rd + q;
                    val = (rd - q) * rsqrtf(fmaxf(den2, 1e-12f));
                }
                out[(size_t)(row0 + lrow) * NSPK + col] = wv * val + bv;
            }
        }
    }
}

extern "C" void kernel_launch(void* const* d_in, const int* in_sizes, int n_in,
                              void* d_out, int out_size, void* d_ws, size_t ws_size,
                              hipStream_t stream) {
    const float* emb = (const float*)d_in[0];
    const float* w   = (const float*)d_in[1];
    const float* b   = (const float*)d_in[2];
    float* out = (float*)d_out;

    const size_t sz_Sp  = (size_t)4 * NSPK * DDIM * 4;
    const size_t sz_ebf = (size_t)NROW * DDIM * 2;
    const size_t sz_cbf = (size_t)NSPK * DDIM * 2;
    const size_t sz_qg  = (size_t)NROW * 4;
    const size_t need = sz_Sp + sz_ebf + sz_cbf + sz_qg + 2 * NSPK * 4;

    if (ws_size >= need) {
        char* p = (char*)d_ws;
        float* Sp = (float*)p;              p += sz_Sp;
        unsigned short* ebf = (unsigned short*)p; p += sz_ebf;
        unsigned short* cbf = (unsigned short*)p; p += sz_cbf;
        float* qg = (float*)p;              p += sz_qg;
        float* n2 = (float*)p;              p += NSPK * 4;
        float* n1 = n2 + NSPK;
        k_prep<<<dim3(NSPK, 4), 256, 0, stream>>>(emb, Sp, ebf, qg);
        k_center<4, 1><<<NSPK, 256, 0, stream>>>(Sp, cbf, n2, n1);
        k_gemm8<<<NROW / 16, 256, 0, stream>>>(ebf, cbf, qg, n2, n1, w, b, out);
    } else {
        float* Sp = (float*)d_ws;
        unsigned short* cbf = (unsigned short*)(Sp + 2 * NSPK * DDIM);
        float* n2 = (float*)(cbf + NSPK * DDIM);
        float* n1 = n2 + NSPK;
        k_sums<<<dim3(NSPK, 2), 256, 0, stream>>>(emb, Sp);
        k_center<2, 0><<<NSPK, 256, 0, stream>>>(Sp, cbf, n2, n1);
        k_gemm_old<<<NROW / 32, 256, 0, stream>>>(emb, cbf, n2, n1, w, b, out);
    }
}

// Round 9
// 131.944 us; speedup vs baseline: 1.3225x; 1.0393x over previous
//
#include <hip/hip_runtime.h>

#define NSPK 256
#define MUTT 64
#define DDIM 1024
#define NROW (NSPK * MUTT)   // 16384

using frag_ab = __attribute__((ext_vector_type(8))) short;   // 8 bf16 (4 VGPRs)
using frag_cd = __attribute__((ext_vector_type(4))) float;   // 4 fp32 acc

static __device__ __forceinline__ unsigned short f32_to_bf16(float f) {
    unsigned int u = __float_as_uint(f);
    return (unsigned short)((u + 0x7FFFu + ((u >> 16) & 1u)) >> 16);   // RNE
}
static __device__ __forceinline__ unsigned int pack2(float a, float b) {
    return (unsigned)f32_to_bf16(a) | ((unsigned)f32_to_bf16(b) << 16);
}
static __device__ __forceinline__ void gload16(const void* g, void* l) {
    __builtin_amdgcn_global_load_lds(
        (const __attribute__((address_space(1))) unsigned int*)g,
        (__attribute__((address_space(3))) unsigned int*)l, 16, 0, 0);
}

// ======================= FAST PATH =======================

// k_prep v3: PURE STREAM — no LDS, no shuffles, no q.
// grid (NSPK, 4), 256 thr. Thread t: rows (t>>7)*8..+8 of the block's 16,
// cols (t&127)*8..+8. Emits bf16 cast (uint4 stores) + 8 S-partials.
__global__ void __launch_bounds__(256) k_prep(const float* __restrict__ emb,
                                              float* __restrict__ Sp,
                                              unsigned short* __restrict__ ebf) {
    const int j = blockIdx.x;
    const int h = blockIdx.y;
    const int t = threadIdx.x;
    const int half = t >> 7;               // 0/1: which 8 rows
    const int c8 = (t & 127) * 8;          // column base
    const size_t rowbase = (size_t)j * MUTT + (size_t)h * 16 + (size_t)half * 8;
    const float* src = emb + rowbase * DDIM + c8;
    unsigned short* dst = ebf + rowbase * DDIM + c8;
    float4 s0 = make_float4(0.f, 0.f, 0.f, 0.f);
    float4 s1 = make_float4(0.f, 0.f, 0.f, 0.f);
    #pragma unroll
    for (int m = 0; m < 8; ++m) {
        float4 a = *(const float4*)(src + (size_t)m * DDIM);
        float4 b = *(const float4*)(src + (size_t)m * DDIM + 4);
        s0.x += a.x; s0.y += a.y; s0.z += a.z; s0.w += a.w;
        s1.x += b.x; s1.y += b.y; s1.z += b.z; s1.w += b.w;
        uint4 pk = make_uint4(pack2(a.x, a.y), pack2(a.z, a.w),
                              pack2(b.x, b.y), pack2(b.z, b.w));
        *(uint4*)(dst + (size_t)m * DDIM) = pk;
    }
    float* sp = Sp + ((size_t)(h * 2 + half) * NSPK + j) * DDIM + c8;
    *(float4*)sp = s0;
    *(float4*)(sp + 4) = s1;
}

// k_center<P, PACKED>: sum P partials -> centers. PACKED=1 writes MFMA-fragment
// order: short index ((k>>3)*256 + j)*8 + (k&7)  (so B-frag loads coalesce).
template <int P, int PACKED>
__global__ void k_center(const float* __restrict__ Sp, unsigned short* __restrict__ cbf,
                         float* __restrict__ normS2g, float* __restrict__ normSg) {
    const int j = blockIdx.x;
    const int t = threadIdx.x;                 // k = 4t .. 4t+3
    float4 v = make_float4(0.f, 0.f, 0.f, 0.f);
    #pragma unroll
    for (int p = 0; p < P; ++p) {
        float4 a = *(const float4*)(Sp + ((size_t)p * NSPK + j) * DDIM + (size_t)t * 4);
        v.x += a.x; v.y += a.y; v.z += a.z; v.w += a.w;
    }
    float sq = v.x * v.x + v.y * v.y + v.z * v.z + v.w * v.w;
    #pragma unroll
    for (int off = 32; off > 0; off >>= 1) sq += __shfl_down(sq, off, 64);
    __shared__ float ws[4];
    __shared__ float sc_sh;
    const int lane = t & 63, wave = t >> 6;
    if (lane == 0) ws[wave] = sq;
    __syncthreads();
    if (t == 0) {
        float tot = ws[0] + ws[1] + ws[2] + ws[3];
        normS2g[j] = tot;
        normSg[j]  = sqrtf(tot);
        float msq = tot * (1.0f / 4096.0f);
        sc_sh = rsqrtf(fmaxf(msq, 1e-12f)) * (1.0f / 64.0f);
    }
    __syncthreads();
    const float sc = sc_sh;
    uint2 pk = make_uint2(pack2(v.x * sc, v.y * sc), pack2(v.z * sc, v.w * sc));
    if (PACKED) {
        unsigned short* dstp = cbf + (((size_t)(t >> 1) * 256 + j) * 8 + (size_t)(t & 1) * 4);
        *(uint2*)dstp = pk;
    } else {
        *(uint2*)(cbf + (size_t)j * DDIM + (size_t)t * 4) = pk;
    }
}

// k_gemm9: 32 rows x 256 cols, grid 512 (2 blocks/CU, 8 waves/CU).
// A (32 x 1024 bf16 = 64 KB) staged once via gload16 + XOR swizzle (1 barrier).
// B zero-distance loads from packed layout (contiguous per quad). Per K-step:
// 2 A ds_reads + 4 B loads + 8 main MFMAs + 2 self-MFMAs (q = diag(A A^T)).
__global__ void __launch_bounds__(256, 2)
k_gemm9(const unsigned short* __restrict__ ebf, const unsigned short* __restrict__ cbfp,
        const float* __restrict__ n2g, const float* __restrict__ n1g,
        const float* __restrict__ wp, const float* __restrict__ bp,
        float* __restrict__ out) {
    __shared__ unsigned short As[32 * DDIM];   // 64 KB
    __shared__ float qsh[32];

    const int tid = threadIdx.x, lane = tid & 63, wave = tid >> 6;
    const int row0 = blockIdx.x * 32;
    const int quad = lane >> 4;
    const int m16 = lane & 15;

    // ---- stage A: 32 rows x 128 chunks(16B) = 16 rounds x 256 thr ----
    // LDS chunk p of row rw holds global chunk p^(rw&7).
    {
        const char* ag = (const char*)(ebf + (size_t)row0 * DDIM);
        char* Ab = (char*)As;
        #pragma unroll
        for (int r = 0; r < 16; ++r) {
            const int c = r * 256 + tid;           // 0..4095
            const int rw = c >> 7;                 // wave-uniform row 0..31
            const int p = c & 127;
            gload16(ag + rw * 2048 + ((p ^ (rw & 7)) << 4), Ab + rw * 2048 + (p << 4));
        }
    }

    // B addressing (packed): byte addr = ((ks*4+quad)*256 + col) * 16
    const char* bq[4];
    #pragma unroll
    for (int cc = 0; cc < 4; ++cc)
        bq[cc] = (const char*)cbfp + ((size_t)quad * 256 + (wave * 64 + cc * 16 + m16)) * 16;

    frag_cd acc[2][4], accq[2];
    #pragma unroll
    for (int rr = 0; rr < 2; ++rr) {
        accq[rr] = (frag_cd){0.f, 0.f, 0.f, 0.f};
        #pragma unroll
        for (int cc = 0; cc < 4; ++cc) acc[rr][cc] = (frag_cd){0.f, 0.f, 0.f, 0.f};
    }

    __syncthreads();   // drains A staging

    const char* Ar0 = (const char*)As + m16 * 2048;          // rows 0..15
    const char* Ar1 = (const char*)As + (16 + m16) * 2048;   // rows 16..31
    const int asw = m16 & 7;                                 // same for row+16
    #pragma unroll 2
    for (int ks = 0; ks < 32; ++ks) {
        const int co = ((((ks << 2) + quad) ^ asw) << 4);
        frag_ab af0 = *(const frag_ab*)(Ar0 + co);
        frag_ab af1 = *(const frag_ab*)(Ar1 + co);
        frag_ab bf0 = *(const frag_ab*)(bq[0] + (size_t)ks * 16384);
        frag_ab bf1 = *(const frag_ab*)(bq[1] + (size_t)ks * 16384);
        frag_ab bf2 = *(const frag_ab*)(bq[2] + (size_t)ks * 16384);
        frag_ab bf3 = *(const frag_ab*)(bq[3] + (size_t)ks * 16384);
        acc[0][0] = __builtin_amdgcn_mfma_f32_16x16x32_bf16(af0, bf0, acc[0][0], 0, 0, 0);
        acc[0][1] = __builtin_amdgcn_mfma_f32_16x16x32_bf16(af0, bf1, acc[0][1], 0, 0, 0);
        acc[0][2] = __builtin_amdgcn_mfma_f32_16x16x32_bf16(af0, bf2, acc[0][2], 0, 0, 0);
        acc[0][3] = __builtin_amdgcn_mfma_f32_16x16x32_bf16(af0, bf3, acc[0][3], 0, 0, 0);
        acc[1][0] = __builtin_amdgcn_mfma_f32_16x16x32_bf16(af1, bf0, acc[1][0], 0, 0, 0);
        acc[1][1] = __builtin_amdgcn_mfma_f32_16x16x32_bf16(af1, bf1, acc[1][1], 0, 0, 0);
        acc[1][2] = __builtin_amdgcn_mfma_f32_16x16x32_bf16(af1, bf2, acc[1][2], 0, 0, 0);
        acc[1][3] = __builtin_amdgcn_mfma_f32_16x16x32_bf16(af1, bf3, acc[1][3], 0, 0, 0);
        accq[0] = __builtin_amdgcn_mfma_f32_16x16x32_bf16(af0, af0, accq[0], 0, 0, 0);
        accq[1] = __builtin_amdgcn_mfma_f32_16x16x32_bf16(af1, af1, accq[1], 0, 0, 0);
    }

    // extract q = diag(accq): element (i,i) lives in lane m16==i, quad==i>>2, reg i&3
    if (wave == 0) {
        #pragma unroll
        for (int rr = 0; rr < 2; ++rr)
            #pragma unroll
            for (int r2 = 0; r2 < 4; ++r2)
                if (m16 == (quad << 2) + r2) qsh[rr * 16 + m16] = accq[rr][r2];
    }
    __syncthreads();

    const float wv = wp[0], bv = bp[0];
    const int jspk = row0 >> 6;            // 32-row block lies inside one speaker
    const float ns2 = n2g[jspk], ns = n1g[jspk];
    #pragma unroll
    for (int rr = 0; rr < 2; ++rr) {
        const int rbase = rr * 16 + (quad << 2);
        #pragma unroll
        for (int cc = 0; cc < 4; ++cc) {
            int col = wave * 64 + cc * 16 + m16;
            frag_cd v = acc[rr][cc];
            #pragma unroll
            for (int r2 = 0; r2 < 4; ++r2) {
                int lrow = rbase + r2;
                float val = v[r2];
                if (col == jspk) {
                    float q = qsh[lrow];
                    float rd = val * ns;
                    float den2 = ns2 - 2.f * rd + q;
                    val = (rd - q) * rsqrtf(fmaxf(den2, 1e-12f));
                }
                out[(size_t)(row0 + lrow) * NSPK + col] = wv * val + bv;
            }
        }
    }
}

// ======================= FALLBACK (small ws) =======================

__global__ void k_sums(const float* __restrict__ emb, float* __restrict__ Sp) {
    const int j = blockIdx.x;
    const int h = blockIdx.y;
    const int c = threadIdx.x;
    const float* base = emb + ((size_t)j * MUTT + (size_t)h * 32) * DDIM + (size_t)c * 4;
    float4 acc = make_float4(0.f, 0.f, 0.f, 0.f);
    #pragma unroll 8
    for (int m = 0; m < 32; ++m) {
        float4 v = *(const float4*)(base + (size_t)m * DDIM);
        acc.x += v.x; acc.y += v.y; acc.z += v.z; acc.w += v.w;
    }
    *(float4*)(Sp + ((size_t)h * NSPK + j) * DDIM + (size_t)c * 4) = acc;
}

__global__ void __launch_bounds__(256)
k_gemm_old(const float* __restrict__ emb, const unsigned short* __restrict__ cbf,
           const float* __restrict__ normS2g, const float* __restrict__ normSg,
           const float* __restrict__ wp, const float* __restrict__ bp,
           float* __restrict__ out) {
    __shared__ unsigned short Asm[32][32];
    __shared__ unsigned short Bsm[256][32];
    __shared__ float qpart[32][8];
    __shared__ float qfin[32];
    const int tid = threadIdx.x, lane = tid & 63, wave = tid >> 6;
    const int row0 = blockIdx.x * 32;
    const int jspk = row0 >> 6;
    frag_cd acc[2][4];
    #pragma unroll
    for (int rr = 0; rr < 2; ++rr)
        #pragma unroll
        for (int cc = 0; cc < 4; ++cc) acc[rr][cc] = (frag_cd){0.f, 0.f, 0.f, 0.f};
    const int ar = tid >> 3, ak = (tid & 7) << 2;
    const float* aptr = emb + (size_t)(row0 + ar) * DDIM + ak;
    float qacc = 0.f;
    const int bi = tid >> 2, bk = (tid & 3) << 3;
    const int am = lane & 15, kq = (lane >> 4) << 3;
    for (int k0 = 0; k0 < DDIM; k0 += 32) {
        __syncthreads();
        float4 av = *(const float4*)(aptr + k0);
        qacc += av.x * av.x + av.y * av.y + av.z * av.z + av.w * av.w;
        *(uint2*)&Asm[ar][ak] = make_uint2(pack2(av.x, av.y), pack2(av.z, av.w));
        #pragma unroll
        for (int p = 0; p < 4; ++p) {
            int brow = p * 64 + bi;
            *(uint4*)&Bsm[brow][bk] = *(const uint4*)(cbf + (size_t)brow * DDIM + k0 + bk);
        }
        __syncthreads();
        frag_ab afr[2], bfr[4];
        #pragma unroll
        for (int rr = 0; rr < 2; ++rr) afr[rr] = *(const frag_ab*)&Asm[rr * 16 + am][kq];
        #pragma unroll
        for (int cc = 0; cc < 4; ++cc) bfr[cc] = *(const frag_ab*)&Bsm[wave * 64 + cc * 16 + am][kq];
        #pragma unroll
        for (int rr = 0; rr < 2; ++rr)
            #pragma unroll
            for (int cc = 0; cc < 4; ++cc)
                acc[rr][cc] = __builtin_amdgcn_mfma_f32_16x16x32_bf16(afr[rr], bfr[cc], acc[rr][cc], 0, 0, 0);
    }
    qpart[ar][tid & 7] = qacc;
    __syncthreads();
    if (tid < 32) {
        float s = 0.f;
        #pragma unroll
        for (int u = 0; u < 8; ++u) s += qpart[tid][u];
        qfin[tid] = s;
    }
    __syncthreads();
    const float wv = wp[0], bv = bp[0];
    const float ns2 = normS2g[jspk], ns = normSg[jspk];
    #pragma unroll
    for (int rr = 0; rr < 2; ++rr) {
        int rbase = rr * 16 + ((lane >> 4) << 2);
        #pragma unroll
        for (int cc = 0; cc < 4; ++cc) {
            int col = wave * 64 + cc * 16 + (lane & 15);
            frag_cd v = acc[rr][cc];
            #pragma unroll
            for (int r2 = 0; r2 < 4; ++r2) {
                int lrow = rbase + r2;
                float val = v[r2];
                if (col == jspk) {
                    float q = qfin[lrow];
                    float rd = val * ns;
                    float den2 = ns2 - 2.f * rd + q;
                    val = (rd - q) * rsqrtf(fmaxf(den2, 1e-12f));
                }
                out[(size_t)(row0 + lrow) * NSPK + col] = wv * val + bv;
            }
        }
    }
}

extern "C" void kernel_launch(void* const* d_in, const int* in_sizes, int n_in,
                              void* d_out, int out_size, void* d_ws, size_t ws_size,
                              hipStream_t stream) {
    const float* emb = (const float*)d_in[0];
    const float* w   = (const float*)d_in[1];
    const float* b   = (const float*)d_in[2];
    float* out = (float*)d_out;

    const size_t sz_Sp  = (size_t)8 * NSPK * DDIM * 4;     // 8 partials
    const size_t sz_ebf = (size_t)NROW * DDIM * 2;
    const size_t sz_cbf = (size_t)NSPK * DDIM * 2;
    const size_t need = sz_Sp + sz_ebf + sz_cbf + 2 * NSPK * 4;

    if (ws_size >= need) {
        char* p = (char*)d_ws;
        float* Sp = (float*)p;              p += sz_Sp;
        unsigned short* ebf = (unsigned short*)p; p += sz_ebf;
        unsigned short* cbf = (unsigned short*)p; p += sz_cbf;
        float* n2 = (float*)p;              p += NSPK * 4;
        float* n1 = (float*)p;
        k_prep<<<dim3(NSPK, 4), 256, 0, stream>>>(emb, Sp, ebf);
        k_center<8, 1><<<NSPK, 256, 0, stream>>>(Sp, cbf, n2, n1);
        k_gemm9<<<NROW / 32, 256, 0, stream>>>(ebf, cbf, n2, n1, w, b, out);
    } else {
        float* Sp = (float*)d_ws;
        unsigned short* cbf = (unsigned short*)(Sp + 2 * NSPK * DDIM);
        float* n2 = (float*)(cbf + NSPK * DDIM);
        float* n1 = n2 + NSPK;
        k_sums<<<dim3(NSPK, 2), 256, 0, stream>>>(emb, Sp);
        k_center<2, 0><<<NSPK, 256, 0, stream>>>(Sp, cbf, n2, n1);
        k_gemm_old<<<NROW / 32, 256, 0, stream>>>(emb, cbf, n2, n1, w, b, out);
    }
}